// Round 6
// baseline (237.294 us; speedup 1.0000x reference)
//
#include <hip/hip_runtime.h>
#include <hip/hip_bf16.h>

#define NT 4096   // tokens
#define CD 768    // channels
#define NH 12     // heads
#define HD 64     // head dim
#define CQ 2304   // 3*CD

typedef __bf16 bf;
typedef __bf16 v8bf __attribute__((ext_vector_type(8)));
typedef __bf16 v4bf __attribute__((ext_vector_type(4)));
typedef short  v4ss __attribute__((ext_vector_type(4)));
typedef float  v4f  __attribute__((ext_vector_type(4)));

// async global->LDS, 16B per lane; LDS dest must be wave-uniform base + lane*16
__device__ __forceinline__ void gld16(const bf* g, bf* l) {
  __builtin_amdgcn_global_load_lds(
      (__attribute__((address_space(1))) void*)g,
      (__attribute__((address_space(3))) void*)l,
      16, 0, 0);
}

__device__ __forceinline__ float fexp2(float x) {
#if defined(__HIP_DEVICE_COMPILE__)
  return __builtin_amdgcn_exp2f(x);
#else
  return x;  // host pass never executes device code
#endif
}

// 16x16x16 bf16 MFMA (v_mfma_f32_16x16x16_bf16, clang name ..16x16x16bf16_1k):
// A/B = 4 bf16 per lane (m=lane&15, k=quad*4+j); C/D layout same as x32 variant.
__device__ __forceinline__ v4f mfma16(v4bf a, v4bf b, v4f c) {
#if defined(__HIP_DEVICE_COMPILE__)
  return __builtin_amdgcn_mfma_f32_16x16x16bf16_1k(
      __builtin_bit_cast(v4ss, a), __builtin_bit_cast(v4ss, b), c, 0, 0, 0);
#else
  (void)a; (void)b;
  return c;  // host pass never executes device code
#endif
}

// ---------------- fp32 -> bf16 cast (vectorized) ----------------
__global__ void cast_f32_bf16(const float* __restrict__ in, bf* __restrict__ out, int n4) {
  const int i = blockIdx.x * blockDim.x + threadIdx.x;
  if (i < n4) {
    const float4 v = ((const float4*)in)[i];
    bf o4[4] = {(bf)v.x, (bf)v.y, (bf)v.z, (bf)v.w};
    ((ushort4*)out)[i] = *(const ushort4*)o4;
  }
}

// ---------------- fp32 transpose + cast to bf16: out[c][r] = (bf)in[r][c] ----------------
__global__ void tr_cast(const float* __restrict__ in, bf* __restrict__ out,
                        int rows, int cols) {
  __shared__ float tile[32][33];
  const int c0 = blockIdx.x * 32, r0 = blockIdx.y * 32;
  const int tx = threadIdx.x, ty = threadIdx.y;  // 32 x 8
#pragma unroll
  for (int j = 0; j < 32; j += 8)
    tile[ty + j][tx] = in[(size_t)(r0 + ty + j) * cols + (c0 + tx)];
  __syncthreads();
#pragma unroll
  for (int j = 0; j < 32; j += 8)
    out[(size_t)(c0 + ty + j) * rows + (r0 + tx)] = (bf)tile[tx][ty + j];
}

// ------------- QKV GEMM: Xb[4096x768] * WqkvT[2304x768]^T, scatter epilogue -------------
__global__ __launch_bounds__(256) void gemm_qkv(
    const bf* __restrict__ A, const bf* __restrict__ Bt,
    bf* __restrict__ Qb, bf* __restrict__ Kb, bf* __restrict__ Vtb) {
  __shared__ __align__(16) bf As[128 * 32];
  __shared__ __align__(16) bf Bs[128 * 32];
  const int tid = threadIdx.x;
  const int lane = tid & 63, wave = tid >> 6;
  const int lane15 = lane & 15, quad = lane >> 4;
  const int waveM = wave & 1, waveN = wave >> 1;
  const int bm = blockIdx.x * 128;
  const int bn = blockIdx.y * 128;

  v4f acc[4][4];
#pragma unroll
  for (int i = 0; i < 4; ++i)
#pragma unroll
    for (int j = 0; j < 4; ++j) acc[i][j] = (v4f){0.f, 0.f, 0.f, 0.f};

  for (int k0 = 0; k0 < CD; k0 += 32) {
#pragma unroll
    for (int p = 0; p < 2; ++p) {
      const int t = tid + p * 256;
      const int r = t >> 2, c = (t & 3) * 8;
      gld16(A + (size_t)(bm + r) * CD + k0 + c, As + t * 8);
    }
#pragma unroll
    for (int p = 0; p < 2; ++p) {
      const int t = tid + p * 256;
      const int r = t >> 2, c = (t & 3) * 8;
      gld16(Bt + (size_t)(bn + r) * CD + k0 + c, Bs + t * 8);
    }
    asm volatile("s_waitcnt vmcnt(0)" ::: "memory");
    __syncthreads();

    v8bf af[4], bfr[4];
#pragma unroll
    for (int mt = 0; mt < 4; ++mt)
      af[mt] = *(const v8bf*)(As + (waveM * 64 + mt * 16 + lane15) * 32 + quad * 8);
#pragma unroll
    for (int nt = 0; nt < 4; ++nt)
      bfr[nt] = *(const v8bf*)(Bs + (waveN * 64 + nt * 16 + lane15) * 32 + quad * 8);
#pragma unroll
    for (int mt = 0; mt < 4; ++mt)
#pragma unroll
      for (int nt = 0; nt < 4; ++nt)
        acc[mt][nt] = __builtin_amdgcn_mfma_f32_16x16x32_bf16(af[mt], bfr[nt], acc[mt][nt], 0, 0, 0);
    __syncthreads();
  }

  const float QSCALE = 0.125f * 1.4426950408889634f;  // fold D^-0.5 * log2(e)
#pragma unroll
  for (int mt = 0; mt < 4; ++mt) {
    const int rowB = bm + waveM * 64 + mt * 16 + quad * 4;
#pragma unroll
    for (int nt = 0; nt < 4; ++nt) {
      const int col = bn + waveN * 64 + nt * 16 + lane15;
      const int s = col / CD;
      const int rem = col - s * CD;
      const int h = rem >> 6, d = rem & 63;
      if (s == 2) {
        // V^T: lane owns 4 consecutive rows at fixed column -> one 8B store
        bf vp[4];
#pragma unroll
        for (int i = 0; i < 4; ++i) vp[i] = (bf)acc[mt][nt][i];
        *(uint2*)(Vtb + ((size_t)h * HD + d) * NT + rowB) = *(const uint2*)vp;
      } else {
#pragma unroll
        for (int i = 0; i < 4; ++i) {
          const float v = acc[mt][nt][i];
          const int row = rowB + i;
          if (s == 0) Qb[((size_t)h * NT + row) * HD + d] = (bf)(v * QSCALE);
          else        Kb[((size_t)h * NT + row) * HD + d] = (bf)v;
        }
      }
    }
  }
}

// ------------- attention: block = 1 head x 64 Q rows; 4 waves = 2 Q-strips x 2 key-halves ----
// max-free softmax; P never touches LDS: S^T C-layout == x16 MFMA A-layout.
__global__ __launch_bounds__(256, 4) void attn(
    const bf* __restrict__ Qb, const bf* __restrict__ Kb,
    const bf* __restrict__ Vtb, bf* __restrict__ Ob) {
  __shared__ __align__(16) bf Ks[128 * 72];      // 128 keys x 64 dims, pad->72
  __shared__ __align__(16) bf Vs[64 * 136];      // 64 dims x 128 keys, pad->136

  const int h = blockIdx.y;
  const int q0 = blockIdx.x * 64;
  const int tid = threadIdx.x;
  const int wave = tid >> 6, lane = tid & 63;
  const int lane15 = lane & 15, quad = lane >> 4;
  const int wsq = wave & 1;   // Q strip: rows [wsq*32, +32)
  const int wsk = wave >> 1;  // key half: keys [kt + wsk*64, +64)

  const bf* Kh = Kb + (size_t)h * NT * HD;
  const bf* Vh = Vtb + (size_t)h * HD * NT;

  // Q fragments (B-operand of x32: n = lane15 = Q row, k = quad*8+j = dim)
  v8bf aQ[2][2];
#pragma unroll
  for (int sub = 0; sub < 2; ++sub) {
    const int qrow = q0 + wsq * 32 + sub * 16 + lane15;
    aQ[sub][0] = *(const v8bf*)(Qb + ((size_t)h * NT + qrow) * HD + quad * 8);
    aQ[sub][1] = *(const v8bf*)(Qb + ((size_t)h * NT + qrow) * HD + 32 + quad * 8);
  }

  v4f o[2][4];                 // C-layout: col=lane15=dim, row=quad*4+i=Q row
#pragma unroll
  for (int sub = 0; sub < 2; ++sub)
#pragma unroll
    for (int dt = 0; dt < 4; ++dt) o[sub][dt] = (v4f){0.f, 0.f, 0.f, 0.f};
  float lsum[2] = {0.f, 0.f};

  const bf* Kw = Ks + wsk * 64 * 72;
  const bf* Vw = Vs + wsk * 64;

  for (int kt = 0; kt < NT; kt += 128) {
    // stage K 128x64 and V^T 64x128 into padded LDS
#pragma unroll
    for (int p = 0; p < 4; ++p) {
      const int u = tid + p * 256;
      const int r = u >> 3, c = (u & 7) * 8;
      *(uint4*)(Ks + r * 72 + c) = *(const uint4*)(Kh + (size_t)(kt + r) * HD + c);
    }
#pragma unroll
    for (int p = 0; p < 4; ++p) {
      const int u = tid + p * 256;
      const int r = u >> 4, c = (u & 15) * 8;
      *(uint4*)(Vs + r * 136 + c) = *(const uint4*)(Vh + (size_t)r * NT + kt + c);
    }
    __syncthreads();

    // per 16-key chunk n: S^T = K Q^T (x32, K from LDS, Q regs), then exp in
    // regs -> P is directly an x16 A-frag; O += P*V (V b64 B-frags from LDS)
#pragma unroll
    for (int n = 0; n < 4; ++n) {
      const v8bf bk0 = *(const v8bf*)(Kw + (n * 16 + lane15) * 72 + quad * 8);
      const v8bf bk1 = *(const v8bf*)(Kw + (n * 16 + lane15) * 72 + 32 + quad * 8);
      v4bf aP[2];
#pragma unroll
      for (int sub = 0; sub < 2; ++sub) {
        v4f z = (v4f){0.f, 0.f, 0.f, 0.f};
        z = __builtin_amdgcn_mfma_f32_16x16x32_bf16(bk0, aQ[sub][0], z, 0, 0, 0);
        z = __builtin_amdgcn_mfma_f32_16x16x32_bf16(bk1, aQ[sub][1], z, 0, 0, 0);
#pragma unroll
        for (int r = 0; r < 4; ++r) {
          const float p = fexp2(z[r]);
          lsum[sub] += p;
          aP[sub][r] = (bf)p;
        }
      }
#pragma unroll
      for (int dt = 0; dt < 4; ++dt) {
        const v4bf bv = *(const v4bf*)(Vw + (dt * 16 + lane15) * 136 + n * 16 + quad * 4);
        o[0][dt] = mfma16(aP[0], bv, o[0][dt]);
        o[1][dt] = mfma16(aP[1], bv, o[1][dt]);
      }
    }
    __syncthreads();
  }

  // reduce partial denoms across quads (lane then holds denom for Qrow=lane15, its half)
#pragma unroll
  for (int sub = 0; sub < 2; ++sub) {
    lsum[sub] += __shfl_xor(lsum[sub], 16, 64);
    lsum[sub] += __shfl_xor(lsum[sub], 32, 64);
  }

  // cross key-half combine via LDS (reuse Ks)
  float* Cmb = (float*)Ks;  // 2 strips x [32 rows][68 dwords]; col 64 = lsum
  if (wsk == 0) {
#pragma unroll
    for (int sub = 0; sub < 2; ++sub) {
#pragma unroll
      for (int dt = 0; dt < 4; ++dt)
#pragma unroll
        for (int i = 0; i < 4; ++i)
          Cmb[wsq * 2176 + (sub * 16 + quad * 4 + i) * 68 + dt * 16 + lane15] = o[sub][dt][i];
      if (quad == 0)
        Cmb[wsq * 2176 + (sub * 16 + lane15) * 68 + 64] = lsum[sub];
    }
  }
  __syncthreads();
  if (wsk == 1) {
#pragma unroll
    for (int sub = 0; sub < 2; ++sub) {
      const float ltot = lsum[sub] + Cmb[wsq * 2176 + (sub * 16 + lane15) * 68 + 64];
      const float linv = 1.f / ltot;
#pragma unroll
      for (int i = 0; i < 4; ++i) {
        const float linv_i = __shfl(linv, quad * 4 + i, 64);
        const int row = q0 + wsq * 32 + sub * 16 + quad * 4 + i;
#pragma unroll
        for (int dt = 0; dt < 4; ++dt) {
          const float val = o[sub][dt][i] +
              Cmb[wsq * 2176 + (sub * 16 + quad * 4 + i) * 68 + dt * 16 + lane15];
          Ob[(size_t)row * CD + h * HD + dt * 16 + lane15] = (bf)(val * linv_i);
        }
      }
    }
  }
}

// ------------- proj GEMM: Ob[4096x768] * WpT[768x768]^T + bias -> out fp32 -------------
__global__ __launch_bounds__(256) void gemm_proj(
    const bf* __restrict__ A, const bf* __restrict__ Bt,
    const float* __restrict__ bias, float* __restrict__ out) {
  __shared__ __align__(16) bf As[128 * 32];
  __shared__ __align__(16) bf Bs[128 * 32];
  const int tid = threadIdx.x;
  const int lane = tid & 63, wave = tid >> 6;
  const int lane15 = lane & 15, quad = lane >> 4;
  const int waveM = wave & 1, waveN = wave >> 1;
  const int bm = blockIdx.x * 128;
  const int bn = blockIdx.y * 128;

  v4f acc[4][4];
#pragma unroll
  for (int i = 0; i < 4; ++i)
#pragma unroll
    for (int j = 0; j < 4; ++j) acc[i][j] = (v4f){0.f, 0.f, 0.f, 0.f};

  for (int k0 = 0; k0 < CD; k0 += 32) {
#pragma unroll
    for (int p = 0; p < 2; ++p) {
      const int t = tid + p * 256;
      const int r = t >> 2, c = (t & 3) * 8;
      gld16(A + (size_t)(bm + r) * CD + k0 + c, As + t * 8);
    }
#pragma unroll
    for (int p = 0; p < 2; ++p) {
      const int t = tid + p * 256;
      const int r = t >> 2, c = (t & 3) * 8;
      gld16(Bt + (size_t)(bn + r) * CD + k0 + c, Bs + t * 8);
    }
    asm volatile("s_waitcnt vmcnt(0)" ::: "memory");
    __syncthreads();

    v8bf af[4], bfr[4];
#pragma unroll
    for (int mt = 0; mt < 4; ++mt)
      af[mt] = *(const v8bf*)(As + (waveM * 64 + mt * 16 + lane15) * 32 + quad * 8);
#pragma unroll
    for (int nt = 0; nt < 4; ++nt)
      bfr[nt] = *(const v8bf*)(Bs + (waveN * 64 + nt * 16 + lane15) * 32 + quad * 8);
#pragma unroll
    for (int mt = 0; mt < 4; ++mt)
#pragma unroll
      for (int nt = 0; nt < 4; ++nt)
        acc[mt][nt] = __builtin_amdgcn_mfma_f32_16x16x32_bf16(af[mt], bfr[nt], acc[mt][nt], 0, 0, 0);
    __syncthreads();
  }

#pragma unroll
  for (int mt = 0; mt < 4; ++mt) {
    const int rowB = bm + waveM * 64 + mt * 16 + quad * 4;
#pragma unroll
    for (int nt = 0; nt < 4; ++nt) {
      const int col = bn + waveN * 64 + nt * 16 + lane15;
      const float bcol = bias[col];
#pragma unroll
      for (int i = 0; i < 4; ++i)
        out[(size_t)(rowB + i) * CD + col] = acc[mt][nt][i] + bcol;
    }
  }
}

extern "C" void kernel_launch(void* const* d_in, const int* in_sizes, int n_in,
                              void* d_out, int out_size, void* d_ws, size_t ws_size,
                              hipStream_t stream) {
  const float* x     = (const float*)d_in[0];   // [4096][768] fp32
  const float* wqkv  = (const float*)d_in[1];   // [768][2304] fp32
  const float* wproj = (const float*)d_in[2];   // [768][768]  fp32
  const float* bproj = (const float*)d_in[3];   // [768]       fp32
  float* out = (float*)d_out;                   // [4096][768] fp32

  bf* ws    = (bf*)d_ws;
  bf* Xb    = ws;  ws += (size_t)NT * CD;        // [4096][768] bf16
  bf* WqkvT = ws;  ws += (size_t)CQ * CD;        // [2304][768]
  bf* WpT   = ws;  ws += (size_t)CD * CD;        // [768][768]
  bf* Qb    = ws;  ws += (size_t)NH * NT * HD;   // [h][n][d], pre-scaled by 0.125*log2e
  bf* Kb    = ws;  ws += (size_t)NH * NT * HD;   // [h][n][d]
  bf* Vtb   = ws;  ws += (size_t)NH * NT * HD;   // [h][d][n]
  bf* Ob    = ws;  ws += (size_t)NT * CD;        // [n][h*64+d]

  const int n4 = NT * CD / 4;
  cast_f32_bf16<<<(n4 + 255) / 256, 256, 0, stream>>>(x, Xb, n4);
  tr_cast<<<dim3(CQ / 32, CD / 32), dim3(32, 8), 0, stream>>>(wqkv, WqkvT, CD, CQ);
  tr_cast<<<dim3(CD / 32, CD / 32), dim3(32, 8), 0, stream>>>(wproj, WpT, CD, CD);
  gemm_qkv<<<dim3(NT / 128, CQ / 128), 256, 0, stream>>>(Xb, WqkvT, Qb, Kb, Vtb);
  attn<<<dim3(NT / 64, NH), 256, 0, stream>>>(Qb, Kb, Vtb, Ob);
  gemm_proj<<<dim3(NT / 128, CD / 128), 256, 0, stream>>>(Ob, WpT, bproj, out);
}

// Round 7
// 221.899 us; speedup vs baseline: 1.0694x; 1.0694x over previous
//
#include <hip/hip_runtime.h>
#include <hip/hip_bf16.h>

#define NT 4096   // tokens
#define CD 768    // channels
#define NH 12     // heads
#define HD 64     // head dim
#define CQ 2304   // 3*CD

typedef __bf16 bf;
typedef __bf16 v8bf __attribute__((ext_vector_type(8)));
typedef __bf16 v4bf __attribute__((ext_vector_type(4)));
typedef float  v4f  __attribute__((ext_vector_type(4)));

// async global->LDS, 16B per lane; LDS dest must be wave-uniform base + lane*16
__device__ __forceinline__ void gld16(const bf* g, bf* l) {
  __builtin_amdgcn_global_load_lds(
      (__attribute__((address_space(1))) void*)g,
      (__attribute__((address_space(3))) void*)l,
      16, 0, 0);
}

__device__ __forceinline__ float fexp2(float x) {
#if defined(__HIP_DEVICE_COMPILE__)
  return __builtin_amdgcn_exp2f(x);
#else
  return x;  // host pass never executes device code
#endif
}

// ---------------- fp32 -> bf16 cast (vectorized) ----------------
__global__ void cast_f32_bf16(const float* __restrict__ in, bf* __restrict__ out, int n4) {
  const int i = blockIdx.x * blockDim.x + threadIdx.x;
  if (i < n4) {
    const float4 v = ((const float4*)in)[i];
    bf o4[4] = {(bf)v.x, (bf)v.y, (bf)v.z, (bf)v.w};
    ((ushort4*)out)[i] = *(const ushort4*)o4;
  }
}

// ---------------- fp32 transpose + cast to bf16: out[c][r] = (bf)in[r][c] ----------------
__global__ void tr_cast(const float* __restrict__ in, bf* __restrict__ out,
                        int rows, int cols) {
  __shared__ float tile[32][33];
  const int c0 = blockIdx.x * 32, r0 = blockIdx.y * 32;
  const int tx = threadIdx.x, ty = threadIdx.y;  // 32 x 8
#pragma unroll
  for (int j = 0; j < 32; j += 8)
    tile[ty + j][tx] = in[(size_t)(r0 + ty + j) * cols + (c0 + tx)];
  __syncthreads();
#pragma unroll
  for (int j = 0; j < 32; j += 8)
    out[(size_t)(c0 + ty + j) * rows + (r0 + tx)] = (bf)tile[tx][ty + j];
}

// ------------- QKV GEMM: Xb[4096x768] * WqkvT[2304x768]^T, scatter epilogue -------------
__global__ __launch_bounds__(256) void gemm_qkv(
    const bf* __restrict__ A, const bf* __restrict__ Bt,
    bf* __restrict__ Qb, bf* __restrict__ Kb, bf* __restrict__ Vtb) {
  __shared__ __align__(16) bf As[128 * 32];
  __shared__ __align__(16) bf Bs[128 * 32];
  const int tid = threadIdx.x;
  const int lane = tid & 63, wave = tid >> 6;
  const int lane15 = lane & 15, quad = lane >> 4;
  const int waveM = wave & 1, waveN = wave >> 1;
  const int bm = blockIdx.x * 128;
  const int bn = blockIdx.y * 128;

  v4f acc[4][4];
#pragma unroll
  for (int i = 0; i < 4; ++i)
#pragma unroll
    for (int j = 0; j < 4; ++j) acc[i][j] = (v4f){0.f, 0.f, 0.f, 0.f};

  for (int k0 = 0; k0 < CD; k0 += 32) {
#pragma unroll
    for (int p = 0; p < 2; ++p) {
      const int t = tid + p * 256;
      const int r = t >> 2, c = (t & 3) * 8;
      gld16(A + (size_t)(bm + r) * CD + k0 + c, As + t * 8);
    }
#pragma unroll
    for (int p = 0; p < 2; ++p) {
      const int t = tid + p * 256;
      const int r = t >> 2, c = (t & 3) * 8;
      gld16(Bt + (size_t)(bn + r) * CD + k0 + c, Bs + t * 8);
    }
    asm volatile("s_waitcnt vmcnt(0)" ::: "memory");
    __syncthreads();

    v8bf af[4], bfr[4];
#pragma unroll
    for (int mt = 0; mt < 4; ++mt)
      af[mt] = *(const v8bf*)(As + (waveM * 64 + mt * 16 + lane15) * 32 + quad * 8);
#pragma unroll
    for (int nt = 0; nt < 4; ++nt)
      bfr[nt] = *(const v8bf*)(Bs + (waveN * 64 + nt * 16 + lane15) * 32 + quad * 8);
#pragma unroll
    for (int mt = 0; mt < 4; ++mt)
#pragma unroll
      for (int nt = 0; nt < 4; ++nt)
        acc[mt][nt] = __builtin_amdgcn_mfma_f32_16x16x32_bf16(af[mt], bfr[nt], acc[mt][nt], 0, 0, 0);
    __syncthreads();
  }

  const float QSCALE = 0.125f * 1.4426950408889634f;  // fold D^-0.5 * log2(e)
#pragma unroll
  for (int mt = 0; mt < 4; ++mt) {
    const int rowB = bm + waveM * 64 + mt * 16 + quad * 4;
#pragma unroll
    for (int nt = 0; nt < 4; ++nt) {
      const int col = bn + waveN * 64 + nt * 16 + lane15;
      const int s = col / CD;
      const int rem = col - s * CD;
      const int h = rem >> 6, d = rem & 63;
      if (s == 2) {
        // V^T: lane owns 4 consecutive rows at fixed column -> one 8B store
        bf vp[4];
#pragma unroll
        for (int i = 0; i < 4; ++i) vp[i] = (bf)acc[mt][nt][i];
        *(uint2*)(Vtb + ((size_t)h * HD + d) * NT + rowB) = *(const uint2*)vp;
      } else {
#pragma unroll
        for (int i = 0; i < 4; ++i) {
          const float v = acc[mt][nt][i];
          const int row = rowB + i;
          if (s == 0) Qb[((size_t)h * NT + row) * HD + d] = (bf)(v * QSCALE);
          else        Kb[((size_t)h * NT + row) * HD + d] = (bf)v;
        }
      }
    }
  }
}

// ------------- attention: block = 1 head x 64 Q rows; wave = 32-key quarter x ALL 64 Q rows ---
// max-free softmax; P stays in registers; PV uses x32 MFMA with a key-permuted V LDS layout
// (MFMA reduces over slots: A and B just need the SAME key order per slot).
__global__ __launch_bounds__(256, 3) void attn(
    const bf* __restrict__ Qb, const bf* __restrict__ Kb,
    const bf* __restrict__ Vtb, bf* __restrict__ Ob) {
  __shared__ __align__(16) char smem[35840];
  bf* Ks = (bf*)smem;              // [128 keys][64 dims pad 72]  = 18432 B
  bf* Vs = (bf*)(smem + 18432);    // [64 dims][128 keys pad 136] = 17408 B (permuted key order)
  float* Red = (float*)smem;       // epilogue reuse: 8 regions x 1024 f + lsum

  const int h = blockIdx.y;
  const int q0 = blockIdx.x * 64;
  const int tid = threadIdx.x;
  const int wave = tid >> 6, lane = tid & 63;
  const int lane15 = lane & 15, quad = lane >> 4;

  const bf* Kh = Kb + (size_t)h * NT * HD;
  const bf* Vh = Vtb + (size_t)h * HD * NT;

  // Q fragments for all 4 sub-tiles (B-operand: n=lane15=Q row, k=quad*8+j=dim)
  v8bf aQ[4][2];
#pragma unroll
  for (int sub = 0; sub < 4; ++sub) {
    const int qrow = q0 + sub * 16 + lane15;
    aQ[sub][0] = *(const v8bf*)(Qb + ((size_t)h * NT + qrow) * HD + quad * 8);
    aQ[sub][1] = *(const v8bf*)(Qb + ((size_t)h * NT + qrow) * HD + 32 + quad * 8);
  }

  v4f o[4][4];                 // [sub][dt], C-layout: col=lane15=dim, row=quad*4+i=Q row
#pragma unroll
  for (int sub = 0; sub < 4; ++sub)
#pragma unroll
    for (int dt = 0; dt < 4; ++dt) o[sub][dt] = (v4f){0.f, 0.f, 0.f, 0.f};
  float lsum[4] = {0.f, 0.f, 0.f, 0.f};

  for (int kt = 0; kt < NT; kt += 128) {
    // stage K 128x64 (row-major, pad 72)
#pragma unroll
    for (int p = 0; p < 4; ++p) {
      const int u = tid + p * 256;
      const int r = u >> 3, c = (u & 7) * 8;
      *(uint4*)(Ks + r * 72 + c) = *(const uint4*)(Kh + (size_t)(kt + r) * HD + c);
    }
    // stage V^T 64x128 with per-32-key-group interleave: pos q*8+j holds
    // key (j<4 ? 4q+j : 16+4q+(j-4)); an 8-key global chunk -> two b64 writes
#pragma unroll
    for (int p = 0; p < 4; ++p) {
      const int u = tid + p * 256;
      const int d = u >> 4, c = (u & 15) * 8;
      const uint4 v = *(const uint4*)(Vh + (size_t)d * NT + kt + c);
      const int t32 = c >> 5, g = (c & 31) >> 3;
      const int pa = ((g & 1) << 4) | ((g >> 1) << 2);
      bf* dst = Vs + d * 136 + t32 * 32 + pa;
      *(uint2*)dst       = make_uint2(v.x, v.y);
      *(uint2*)(dst + 8) = make_uint2(v.z, v.w);
    }
    __syncthreads();

    // S^T = K Q^T on this wave's 32 keys (2 chunks of 16) x all 64 Q rows
    v4bf aPlo[4], aPhi[4];
#pragma unroll
    for (int e = 0; e < 2; ++e) {
      const bf* krow = Ks + ((wave * 2 + e) * 16 + lane15) * 72;
      const v8bf bk0 = *(const v8bf*)(krow + quad * 8);
      const v8bf bk1 = *(const v8bf*)(krow + 32 + quad * 8);
#pragma unroll
      for (int sub = 0; sub < 4; ++sub) {
        v4f z = (v4f){0.f, 0.f, 0.f, 0.f};
        z = __builtin_amdgcn_mfma_f32_16x16x32_bf16(bk0, aQ[sub][0], z, 0, 0, 0);
        z = __builtin_amdgcn_mfma_f32_16x16x32_bf16(bk1, aQ[sub][1], z, 0, 0, 0);
        v4bf p4;
#pragma unroll
        for (int r = 0; r < 4; ++r) {
          const float p = fexp2(z[r]);
          lsum[sub] += p;
          p4[r] = (bf)p;
        }
        if (e == 0) aPlo[sub] = p4; else aPhi[sub] = p4;
      }
    }

    // O += P V over this wave's 32 keys: one x32 MFMA per (sub,dt).
    // A slot (q,j) holds key j<4?4q+j:16+4q+j-4 == V's LDS position order.
#pragma unroll
    for (int dt = 0; dt < 4; ++dt) {
      const v8bf bv = *(const v8bf*)(Vs + (dt * 16 + lane15) * 136 + wave * 32 + quad * 8);
#pragma unroll
      for (int sub = 0; sub < 4; ++sub) {
        const v8bf aP8 = __builtin_shufflevector(aPlo[sub], aPhi[sub], 0, 1, 2, 3, 4, 5, 6, 7);
        o[sub][dt] = __builtin_amdgcn_mfma_f32_16x16x32_bf16(aP8, bv, o[sub][dt], 0, 0, 0);
      }
    }
    __syncthreads();
  }

  // quad-reduce denoms: lane then holds denom partial (this wave's 32 keys) for Qrow=lane15
#pragma unroll
  for (int sub = 0; sub < 4; ++sub) {
    lsum[sub] += __shfl_xor(lsum[sub], 16, 64);
    lsum[sub] += __shfl_xor(lsum[sub], 32, 64);
  }

  // cross-wave combine, two phases of 2 subs (LDS budget). Region rw=wave*2+sl:
  // [dt][col=lane15][row] = 1024 floats; lsum at float offset 8192.
#pragma unroll
  for (int sp = 0; sp < 2; ++sp) {
    __syncthreads();
#pragma unroll
    for (int sl = 0; sl < 2; ++sl) {
      const int s = sp * 2 + sl;
      float* reg = Red + (wave * 2 + sl) * 1024;
#pragma unroll
      for (int dt = 0; dt < 4; ++dt)
        *(v4f*)(reg + dt * 256 + lane15 * 16 + quad * 4) = o[s][dt];
      if (quad == 0) Red[8192 + (wave * 2 + sl) * 16 + lane15] = lsum[s];
    }
    __syncthreads();
    const int wlo = sp * 2;  // phase 0: waves 0,1 reduce subs 0,1; phase 1: waves 2,3 -> subs 2,3
    if (wave == wlo || wave == wlo + 1) {
      const int sl = wave - wlo;
      const int s = sp * 2 + sl;
      float den = 0.f;
#pragma unroll
      for (int wv = 0; wv < 4; ++wv) den += Red[8192 + (wv * 2 + sl) * 16 + lane15];
      const float linv = 1.f / den;  // indexed by Qrow-within-sub = lane15
#pragma unroll
      for (int dt = 0; dt < 4; ++dt) {
        v4f sum = (v4f){0.f, 0.f, 0.f, 0.f};
#pragma unroll
        for (int wv = 0; wv < 4; ++wv)
          sum += *(const v4f*)(Red + (wv * 2 + sl) * 1024 + dt * 256 + lane15 * 16 + quad * 4);
#pragma unroll
        for (int i = 0; i < 4; ++i) {
          const float linv_i = __shfl(linv, quad * 4 + i, 64);
          const int row = q0 + s * 16 + quad * 4 + i;
          Ob[(size_t)row * CD + h * HD + dt * 16 + lane15] = (bf)(sum[i] * linv_i);
        }
      }
    }
  }
}

// ------------- proj GEMM: Ob[4096x768] * WpT[768x768]^T + bias -> out fp32 -------------
__global__ __launch_bounds__(256) void gemm_proj(
    const bf* __restrict__ A, const bf* __restrict__ Bt,
    const float* __restrict__ bias, float* __restrict__ out) {
  __shared__ __align__(16) bf As[128 * 32];
  __shared__ __align__(16) bf Bs[128 * 32];
  const int tid = threadIdx.x;
  const int lane = tid & 63, wave = tid >> 6;
  const int lane15 = lane & 15, quad = lane >> 4;
  const int waveM = wave & 1, waveN = wave >> 1;
  const int bm = blockIdx.x * 128;
  const int bn = blockIdx.y * 128;

  v4f acc[4][4];
#pragma unroll
  for (int i = 0; i < 4; ++i)
#pragma unroll
    for (int j = 0; j < 4; ++j) acc[i][j] = (v4f){0.f, 0.f, 0.f, 0.f};

  for (int k0 = 0; k0 < CD; k0 += 32) {
#pragma unroll
    for (int p = 0; p < 2; ++p) {
      const int t = tid + p * 256;
      const int r = t >> 2, c = (t & 3) * 8;
      gld16(A + (size_t)(bm + r) * CD + k0 + c, As + t * 8);
    }
#pragma unroll
    for (int p = 0; p < 2; ++p) {
      const int t = tid + p * 256;
      const int r = t >> 2, c = (t & 3) * 8;
      gld16(Bt + (size_t)(bn + r) * CD + k0 + c, Bs + t * 8);
    }
    asm volatile("s_waitcnt vmcnt(0)" ::: "memory");
    __syncthreads();

    v8bf af[4], bfr[4];
#pragma unroll
    for (int mt = 0; mt < 4; ++mt)
      af[mt] = *(const v8bf*)(As + (waveM * 64 + mt * 16 + lane15) * 32 + quad * 8);
#pragma unroll
    for (int nt = 0; nt < 4; ++nt)
      bfr[nt] = *(const v8bf*)(Bs + (waveN * 64 + nt * 16 + lane15) * 32 + quad * 8);
#pragma unroll
    for (int mt = 0; mt < 4; ++mt)
#pragma unroll
      for (int nt = 0; nt < 4; ++nt)
        acc[mt][nt] = __builtin_amdgcn_mfma_f32_16x16x32_bf16(af[mt], bfr[nt], acc[mt][nt], 0, 0, 0);
    __syncthreads();
  }

#pragma unroll
  for (int mt = 0; mt < 4; ++mt) {
    const int rowB = bm + waveM * 64 + mt * 16 + quad * 4;
#pragma unroll
    for (int nt = 0; nt < 4; ++nt) {
      const int col = bn + waveN * 64 + nt * 16 + lane15;
      const float bcol = bias[col];
#pragma unroll
      for (int i = 0; i < 4; ++i)
        out[(size_t)(rowB + i) * CD + col] = acc[mt][nt][i] + bcol;
    }
  }
}

extern "C" void kernel_launch(void* const* d_in, const int* in_sizes, int n_in,
                              void* d_out, int out_size, void* d_ws, size_t ws_size,
                              hipStream_t stream) {
  const float* x     = (const float*)d_in[0];   // [4096][768] fp32
  const float* wqkv  = (const float*)d_in[1];   // [768][2304] fp32
  const float* wproj = (const float*)d_in[2];   // [768][768]  fp32
  const float* bproj = (const float*)d_in[3];   // [768]       fp32
  float* out = (float*)d_out;                   // [4096][768] fp32

  bf* ws    = (bf*)d_ws;
  bf* Xb    = ws;  ws += (size_t)NT * CD;        // [4096][768] bf16
  bf* WqkvT = ws;  ws += (size_t)CQ * CD;        // [2304][768]
  bf* WpT   = ws;  ws += (size_t)CD * CD;        // [768][768]
  bf* Qb    = ws;  ws += (size_t)NH * NT * HD;   // [h][n][d], pre-scaled by 0.125*log2e
  bf* Kb    = ws;  ws += (size_t)NH * NT * HD;   // [h][n][d]
  bf* Vtb   = ws;  ws += (size_t)NH * NT * HD;   // [h][d][n]
  bf* Ob    = ws;  ws += (size_t)NT * CD;        // [n][h*64+d]

  const int n4 = NT * CD / 4;
  cast_f32_bf16<<<(n4 + 255) / 256, 256, 0, stream>>>(x, Xb, n4);
  tr_cast<<<dim3(CQ / 32, CD / 32), dim3(32, 8), 0, stream>>>(wqkv, WqkvT, CD, CQ);
  tr_cast<<<dim3(CD / 32, CD / 32), dim3(32, 8), 0, stream>>>(wproj, WpT, CD, CD);
  gemm_qkv<<<dim3(NT / 128, CQ / 128), 256, 0, stream>>>(Xb, WqkvT, Qb, Kb, Vtb);
  attn<<<dim3(NT / 64, NH), 256, 0, stream>>>(Qb, Kb, Vtb, Ob);
  gemm_proj<<<dim3(NT / 128, CD / 128), 256, 0, stream>>>(Ob, WpT, bproj, out);
}